// Round 1
// baseline (113.528 us; speedup 1.0000x reference)
//
#include <hip/hip_runtime.h>

// Reference output = _scallop_fixpoint(single_match) only; the RandNet GEMM
// path is dead code. Fixpoint: SIZE=16, N_ITERS=40, diffminmaxprob semiring
// (AND=min, OR=max).
//
//   S[t,v0,v1] = single_match.reshape(16,16,16)
//   M[t0,t1,v0,v1], M[t,t] = S[t]
//   step: r2[t,v0,v2]     = max_v1 min(M[t,t,v0,v1],    S[t,v1,v2])
//         r3[t0,t1,v0,v2] = max_v1 min(M[t0,t1-1,v0,v1], S[t1,v1,v2])  (0 at t1=0)
//         M = max(M, r3); M[t,t] = max(M[t,t], r2)
//
// Key facts used:
//  * t0-slices are independent -> 1 workgroup per t0, slice lives in LDS,
//    2 barriers/step, single kernel launch.
//  * Thread (t1,v0) owns row M[t0,t1,v0,:] in registers (write-through to LDS).
//  * S >= 0 here, so zero rows (mp <= 0) contribute min(mp,s) <= 0 <= r and
//    can be skipped exactly. S has only 5 nonzeros -> almost all work skipped.
//  * LDS padding: S[16][17][16], M[16][16][17] -> <=2-way bank aliasing (free).

#define N_ITERS 40

__global__ __launch_bounds__(256) void scallop_fixpoint_kernel(
    const float* __restrict__ sm, float* __restrict__ out)
{
    __shared__ float S[16][17][16];   // [t][v1][v2], middle dim padded
    __shared__ float M[16][16][17];   // [t1][v0][v1], last dim padded

    const int tid = threadIdx.x;
    const int t0  = blockIdx.x;       // slice index
    const int t1  = tid >> 4;
    const int v0  = tid & 15;
    const bool diag = (t1 == t0);

    // Stage S (4096 floats, coalesced)
    for (int i = tid; i < 4096; i += 256)
        S[i >> 8][(i >> 4) & 15][i & 15] = sm[i];
    __syncthreads();

    // Init: M[t0][t1][v0][:] = (t1==t0) ? S[t0][v0][:] : 0   (rule 1)
    float r[16];
#pragma unroll
    for (int v2 = 0; v2 < 16; ++v2)
        r[v2] = diag ? S[t0][v0][v2] : 0.0f;
#pragma unroll
    for (int v2 = 0; v2 < 16; ++v2)
        M[t1][v0][v2] = r[v2];
    __syncthreads();

    for (int it = 0; it < N_ITERS; ++it) {
        // Snapshot old diagonal row for rule 2 (rule-3 fold mutates r in place)
        float ro[16];
        if (diag) {
#pragma unroll
            for (int j = 0; j < 16; ++j) ro[j] = r[j];
        }

        // rule 3: fold max_v1 min(M[t1-1][v0][v1], S[t1][v1][:])
        if (t1 > 0) {
#pragma unroll
            for (int v1 = 0; v1 < 16; ++v1) {
                float mp = M[t1 - 1][v0][v1];
                if (mp > 0.0f) {            // exact skip: S >= 0, r >= 0
#pragma unroll
                    for (int v2 = 0; v2 < 16; ++v2)
                        r[v2] = fmaxf(r[v2], fminf(mp, S[t1][v1][v2]));
                }
            }
        }

        // rule 2 (diagonal only): fold max_v1 min(ro[v1], S[t0][v1][:])
        if (diag) {
#pragma unroll
            for (int v1 = 0; v1 < 16; ++v1) {
                float dv = ro[v1];
                if (dv > 0.0f) {
#pragma unroll
                    for (int v2 = 0; v2 < 16; ++v2)
                        r[v2] = fmaxf(r[v2], fminf(dv, S[t0][v1][v2]));
                }
            }
        }

        __syncthreads();                    // all reads of old M complete
#pragma unroll
        for (int v2 = 0; v2 < 16; ++v2)
            M[t1][v0][v2] = r[v2];
        __syncthreads();                    // new M visible to all
    }

    // Coalesced slice write: out[t0*4096 + (t1*256 + v0*16 + v1)]
    float* o = out + t0 * 4096;
    for (int i = tid; i < 4096; i += 256)
        o[i] = M[i >> 8][(i >> 4) & 15][i & 15];
}

extern "C" void kernel_launch(void* const* d_in, const int* in_sizes, int n_in,
                              void* d_out, int out_size, void* d_ws, size_t ws_size,
                              hipStream_t stream) {
    // inputs: 0:x 1:fc1_w 2:fc1_b 3:fc2_w 4:fc2_b 5:single_match (all f32)
    const float* sm = (const float*)d_in[5];
    float* out = (float*)d_out;       // 65536 f32
    (void)in_sizes; (void)n_in; (void)out_size; (void)d_ws; (void)ws_size;
    scallop_fixpoint_kernel<<<dim3(16), dim3(256), 0, stream>>>(sm, out);
}

// Round 2
// 23.350 us; speedup vs baseline: 4.8620x; 4.8620x over previous
//
#include <hip/hip_runtime.h>

// Reference output = _scallop_fixpoint(single_match) only; RandNet GEMMs are
// dead code. Fixpoint over diffminmaxprob semiring (AND=min, OR=max):
//   S[t,v1,v2]; M[t0,t1,v0,v1]; M[t,t]=S[t]
//   step: r2[t]     = D[t] (x) S[t]          (diagonal only)
//         r3[t0,t1] = M[t0,t1-1] (x) S[t1]   (step-start M; zero at t1=0)
//         M = max(M, r3); M[t,t] = max(M[t,t], r2)
// where (A (x) B)[v0,v2] = max_v1 min(A[v0,v1], B[v1,v2]).
//
// Structure (all exact, input-dependent):
//  * t0-slices independent -> 16 blocks of 64 threads, ONE WAVE each:
//    __syncthreads degenerates to a waitcnt (no s_barrier wait cost).
//  * Lane l owns 4 rows (t1 = i*4 + l/16, v0 = l%16) in registers r[4][16];
//    LDS mirror M[][][] written only on change (for neighbor reads).
//  * tmask (ballot, SGPR): bit t = S[t] has a nonzero. If S[t1]==0, rule 3 for
//    that row contributes min(mp,0) <= 0 <= r -> skip with ZERO LDS reads.
//    rm[i]: rowmask of S[t1_i] -> skip zero v1 rows. (Exact for S>=0, M>=0,
//    which holds for this problem: values are 0 / 0.5.)
//  * Monotone idempotent step -> stop when a full step changes nothing
//    (identical to running all 40 iterations). This input: block 0 runs 5
//    iterations, blocks 1..15 run 1.
//  * Final M written from registers, float4-coalesced.

#define N_ITERS 40

__global__ __launch_bounds__(64) void scallop_fixpoint_kernel(
    const float* __restrict__ sm, float* __restrict__ out)
{
    __shared__ __align__(16) float S[16][16][16];  // [t][v1][v2]
    __shared__ float M[16][16][17];                // [t1][v0][v1], padded

    const int l  = threadIdx.x;      // 0..63
    const int t0 = blockIdx.x;       // slice
    const int v0 = l & 15;
    const int g  = l >> 4;           // 16-lane group: chunk i owns t1 = i*4+g

    // ---- stage S (float4, coalesced) + build masks from ballots ----
    unsigned tmask = 0;              // bit t: any nonzero in S[t] (uniform)
    unsigned rm[4] = {0, 0, 0, 0};   // rowmask of S[i*4+g]: bit v1 = row nonzero
    const float4* sm4 = reinterpret_cast<const float4*>(sm);
#pragma unroll
    for (int j = 0; j < 16; ++j) {   // j == t; lanes cover row v1=l/4, v2=(l%4)*4
        float4 v = sm4[j * 64 + l];
        *reinterpret_cast<float4*>(&S[j][l >> 2][(l & 3) * 4]) = v;
        bool nz = (v.x != 0.f) | (v.y != 0.f) | (v.z != 0.f) | (v.w != 0.f);
        unsigned long long b = __ballot(nz);
        if (b) tmask |= 1u << j;
        unsigned rb = 0;
#pragma unroll
        for (int v1 = 0; v1 < 16; ++v1)
            if ((b >> (4 * v1)) & 0xFull) rb |= 1u << v1;
#pragma unroll
        for (int i = 0; i < 4; ++i)
            if (i * 4 + g == j) rm[i] = rb;
    }
    __syncthreads();

    // ---- init (rule 1): r = diag ? S[t0] row : 0; mirror to LDS ----
    float r[4][16];
#pragma unroll
    for (int i = 0; i < 4; ++i) {
        const int t1 = i * 4 + g;
        const bool diag = (t1 == t0);
#pragma unroll
        for (int v2 = 0; v2 < 16; ++v2) {
            r[i][v2] = diag ? S[t0][v0][v2] : 0.0f;
            M[t1][v0][v2] = r[i][v2];
        }
    }
    __syncthreads();

    // ---- fixpoint iterations with exact early exit ----
    for (int it = 0; it < N_ITERS; ++it) {
        bool changed = false;

        // snapshot step-start diagonal row for rule 2 (static indexing only)
        float ro[16];
#pragma unroll
        for (int i = 0; i < 4; ++i)
            if (i == (t0 >> 2) && g == (t0 & 3)) {
#pragma unroll
                for (int v2 = 0; v2 < 16; ++v2) ro[v2] = r[i][v2];
            }

        // rule 3: r[t1] = max(r[t1], M[t1-1] (x) S[t1])
#pragma unroll
        for (int i = 0; i < 4; ++i) {
            if (((tmask >> (i * 4)) & 0xFu) == 0) continue;  // uniform skip
            const int t1 = i * 4 + g;
            if (t1 == 0) continue;
            if (!((tmask >> t1) & 1u)) continue;             // S[t1] all zero
#pragma unroll
            for (int v1 = 0; v1 < 16; ++v1) {
                if (!((rm[i] >> v1) & 1u)) continue;         // S row zero
                float mp = M[t1 - 1][v0][v1];
                if (mp > 0.0f) {
#pragma unroll
                    for (int v2 = 0; v2 < 16; ++v2) {
                        float c = fminf(mp, S[t1][v1][v2]);
                        if (c > r[i][v2]) { r[i][v2] = c; changed = true; }
                    }
                }
            }
        }

        // rule 2 (diagonal only): r[t0] = max(r[t0], ro (x) S[t0])
#pragma unroll
        for (int i = 0; i < 4; ++i) {
            if (i != (t0 >> 2)) continue;                    // uniform
            if (g != (t0 & 3)) continue;
            if (!((tmask >> t0) & 1u)) continue;
#pragma unroll
            for (int v1 = 0; v1 < 16; ++v1) {
                if (!((rm[i] >> v1) & 1u)) continue;
                float dv = ro[v1];
                if (dv > 0.0f) {
#pragma unroll
                    for (int v2 = 0; v2 < 16; ++v2) {
                        float c = fminf(dv, S[t0][v1][v2]);
                        if (c > r[i][v2]) { r[i][v2] = c; changed = true; }
                    }
                }
            }
        }

        const bool any = __any(changed);
        __syncthreads();                 // step-start M reads complete
        if (!any) break;                 // fixpoint reached: exact

        if (changed) {                   // commit changed lanes' rows
#pragma unroll
            for (int i = 0; i < 4; ++i) {
                const int t1 = i * 4 + g;
#pragma unroll
                for (int v2 = 0; v2 < 16; ++v2)
                    M[t1][v0][v2] = r[i][v2];
            }
        }
        __syncthreads();                 // new M visible (waitcnt, one wave)
    }

    // ---- write out from registers, float4-coalesced ----
    float4* o4 = reinterpret_cast<float4*>(out + t0 * 4096);
#pragma unroll
    for (int i = 0; i < 4; ++i) {
        const int row = i * 64 + l;      // t1*16 + v0
#pragma unroll
        for (int j = 0; j < 4; ++j) {
            float4 w = make_float4(r[i][j * 4 + 0], r[i][j * 4 + 1],
                                   r[i][j * 4 + 2], r[i][j * 4 + 3]);
            o4[row * 4 + j] = w;
        }
    }
}

extern "C" void kernel_launch(void* const* d_in, const int* in_sizes, int n_in,
                              void* d_out, int out_size, void* d_ws, size_t ws_size,
                              hipStream_t stream) {
    // inputs: 0:x 1:fc1_w 2:fc1_b 3:fc2_w 4:fc2_b 5:single_match (all f32)
    const float* sm = (const float*)d_in[5];
    float* out = (float*)d_out;          // 65536 f32
    (void)in_sizes; (void)n_in; (void)out_size; (void)d_ws; (void)ws_size;
    scallop_fixpoint_kernel<<<dim3(16), dim3(64), 0, stream>>>(sm, out);
}